// Round 9
// baseline (573.646 us; speedup 1.0000x reference)
//
#include <hip/hip_runtime.h>
#include <hip/hip_cooperative_groups.h>
#include <math.h>

namespace cg = cooperative_groups;

#define N_NODES 50000
#define N_EDGES 800000
#define DIM 128
#define DEG_CAP 48                      // max deg ~ Poisson(16); far tail ~1e-10/node
#define GRID 512
#define BLOCK 256
#define NTHREADS (GRID * BLOCK)         // 131072
#define NWAVES (NTHREADS / 64)          // 2048
#define NODE_CHUNK ((N_NODES + GRID - 1) / GRID)   // 98
#define NT_MAX (N_NODES / 16 + 8)       // 3133 tiles cover all 8 label buckets
#define E_P1 320000
#define E_P2 560000

typedef __attribute__((ext_vector_type(8))) short short8;
typedef __attribute__((ext_vector_type(4))) float floatx4;

__device__ __forceinline__ unsigned short f2bf(float f) {
    unsigned int u = __float_as_uint(f);
    unsigned int r = (u + 0x7fff + ((u >> 16) & 1)) >> 16;  // RNE
    return (unsigned short)r;
}
__device__ __forceinline__ float bf2f_lo(unsigned int v) { return __uint_as_float(v << 16); }
__device__ __forceinline__ float bf2f_hi(unsigned int v) { return __uint_as_float(v & 0xffff0000u); }

// One cooperative kernel, 5 phases separated by grid.sync().
// __launch_bounds__(256,2): >=2 waves/SIMD -> VGPR<=256 -> 2 blocks/CU -> 512 blocks co-resident.
__global__ __launch_bounds__(BLOCK, 2) void mega_kernel(
        const float* __restrict__ x, const int* __restrict__ src, const int* __restrict__ dst,
        const int* __restrict__ label, const float* __restrict__ W, const float* __restrict__ att,
        float* __restrict__ out,
        unsigned short* __restrict__ oxh,     // bf16: holds xh, overwritten in-place with ox
        unsigned short* __restrict__ Wt,      // bf16 W^T per label
        unsigned short* __restrict__ bucket,  // [N][DEG_CAP] src ids
        float* __restrict__ ai, float* __restrict__ aj,
        int* __restrict__ cnt, int* __restrict__ node_list,
        int* __restrict__ lab_part, int* __restrict__ lab_off, int* __restrict__ lab_cur) {
    cg::grid_group gg = cg::this_grid();
    int t = threadIdx.x;
    int blk = blockIdx.x;
    int gtid = blk * BLOCK + t;
    int wave_gid = gtid >> 6;
    int lane = t & 63;

    __shared__ int lcnt[8], lbase[8], lrank[8];

    // ---------------- P0: zero cnt; per-block label histogram (no global atomics) ----------------
    if (t < 8) lcnt[t] = 0;
    __syncthreads();
    for (int i = gtid; i < N_NODES; i += NTHREADS) cnt[i] = 0;
    int c0 = blk * NODE_CHUNK;
    int c1 = c0 + NODE_CHUNK; if (c1 > N_NODES) c1 = N_NODES;
    for (int i = c0 + t; i < c1; i += BLOCK) {
        int lab = label[i];
        int b = (lab >= 1 && lab <= 7) ? (lab - 1) : 7;
        atomicAdd(&lcnt[b], 1);   // LDS atomic
    }
    __syncthreads();
    if (t < 8) lab_part[blk * 8 + t] = lcnt[t];

    gg.sync();

    // ---------------- P1: block0 reduce+scan labels; all: xh, wt, edges [0,E_P1) ----------------
    if (blk == 0) {
        if (t < 8) {
            int s = 0;
            for (int k = 0; k < GRID; k++) s += lab_part[k * 8 + t];
            lcnt[t] = s;
        }
        __syncthreads();
        if (t == 0) {
            int a = 0;
            for (int i = 0; i < 8; i++) { lab_off[i] = a; lab_cur[i] = a; a += lcnt[i]; }
            lab_off[8] = a;
        }
    }
    {   // xh: fp32 x -> bf16 (into oxh)
        const float4* x4 = (const float4*)x;
        ushort4* xh4 = (ushort4*)oxh;
        for (int i = gtid; i < N_NODES * DIM / 4; i += NTHREADS) {
            float4 v = x4[i];
            ushort4 o;
            o.x = f2bf(v.x); o.y = f2bf(v.y); o.z = f2bf(v.z); o.w = f2bf(v.w);
            xh4[i] = o;
        }
    }
    // wt: W[b][d][c] -> Wt[b][c][d] bf16
    for (int i = gtid; i < 7 * DIM * DIM; i += NTHREADS) {
        int b = i >> 14;
        int d = (i >> 7) & 127;
        int c = i & 127;
        Wt[((size_t)b * DIM + c) * DIM + d] = f2bf(W[i]);
    }
    // edges part 1
    for (int e = gtid; e < E_P1; e += NTHREADS) {
        int s = src[e], d = dst[e];
        int slot = atomicAdd(&cnt[d], 1);
        if (slot < DEG_CAP) bucket[(size_t)d * DEG_CAP + slot] = (unsigned short)s;
    }

    gg.sync();

    // ---------------- P2: bucket_fill node_list + edges [E_P1,E_P2) ----------------
    if (t < 8) { lcnt[t] = 0; lrank[t] = 0; }
    __syncthreads();
    for (int i = c0 + t; i < c1; i += BLOCK) {
        int lab = label[i];
        int b = (lab >= 1 && lab <= 7) ? (lab - 1) : 7;
        atomicAdd(&lcnt[b], 1);
    }
    __syncthreads();
    if (t < 8) lbase[t] = (lcnt[t] > 0) ? atomicAdd(&lab_cur[t], lcnt[t]) : 0;
    __syncthreads();
    for (int i = c0 + t; i < c1; i += BLOCK) {
        int lab = label[i];
        int b = (lab >= 1 && lab <= 7) ? (lab - 1) : 7;
        int r = atomicAdd(&lrank[b], 1);
        node_list[lbase[b] + r] = i;
    }
    for (int e = E_P1 + gtid; e < E_P2; e += NTHREADS) {
        int s = src[e], d = dst[e];
        int slot = atomicAdd(&cnt[d], 1);
        if (slot < DEG_CAP) bucket[(size_t)d * DEG_CAP + slot] = (unsigned short)s;
    }

    gg.sync();

    // ---------------- P3: MFMA transform (wave per 16-node tile) + edges [E_P2,E) ----------------
    {
        int m = lane & 15;
        int quad = lane >> 4;
        for (int tile = wave_gid; tile < NT_MAX; tile += NWAVES) {
            int b = 0, base = 0, tcnt = 0, tt = tile;
            for (; b < 8; b++) {
                int q0 = lab_off[b], q1 = lab_off[b + 1];
                int nt = (q1 - q0 + 15) >> 4;
                if (tt < nt) { base = q0 + tt * 16; tcnt = q1 - base; break; }
                tt -= nt;
            }
            if (b == 8) break;          // beyond last tile; later strides too
            if (tcnt > 16) tcnt = 16;

            floatx4 acc[8];
            #pragma unroll
            for (int nt = 0; nt < 8; nt++) acc[nt] = (floatx4){0.f, 0.f, 0.f, 0.f};

            if (b < 7) {
                int mm = (m < tcnt) ? m : 0;
                int nodeA = node_list[base + mm];
                const unsigned short* xrow = oxh + (size_t)nodeA * DIM;
                short8 afrag[4];
                #pragma unroll
                for (int kk = 0; kk < 4; kk++)
                    afrag[kk] = *(const short8*)(xrow + kk * 32 + quad * 8);

                const unsigned short* WtB = Wt + (size_t)b * DIM * DIM;
                #pragma unroll
                for (int kk = 0; kk < 4; kk++) {
                    #pragma unroll
                    for (int nt = 0; nt < 8; nt++) {
                        short8 bfrag = *(const short8*)(WtB + (size_t)(nt * 16 + m) * DIM + kk * 32 + quad * 8);
                        acc[nt] = __builtin_amdgcn_mfma_f32_16x16x32_bf16(afrag[kk], bfrag, acc[nt], 0, 0, 0);
                    }
                }
            }

            int nodes[4];
            #pragma unroll
            for (int r = 0; r < 4; r++) {
                int rw = quad * 4 + r;
                nodes[r] = node_list[base + ((rw < tcnt) ? rw : 0)];
            }
            float pi[4] = {0.f, 0.f, 0.f, 0.f};
            float pj[4] = {0.f, 0.f, 0.f, 0.f};
            #pragma unroll
            for (int nt = 0; nt < 8; nt++) {
                int c = nt * 16 + m;
                float a1 = att[c];
                float a2 = att[DIM + c];
                #pragma unroll
                for (int r = 0; r < 4; r++) {
                    int rw = quad * 4 + r;
                    if (rw < tcnt) {
                        float xv = x[(size_t)nodes[r] * DIM + c];
                        float v = (b < 7) ? (acc[nt][r] + xv) : xv;
                        oxh[(size_t)nodes[r] * DIM + c] = f2bf(v);
                        pi[r] += v * a1;
                        pj[r] += v * a2;
                    }
                }
            }
            #pragma unroll
            for (int r = 0; r < 4; r++) {
                #pragma unroll
                for (int off = 1; off < 16; off <<= 1) {
                    pi[r] += __shfl_xor(pi[r], off, 64);
                    pj[r] += __shfl_xor(pj[r], off, 64);
                }
                int rw = quad * 4 + r;
                if (m == 0 && rw < tcnt) {
                    ai[nodes[r]] = pi[r];
                    aj[nodes[r]] = pj[r];
                }
            }
        }
    }
    for (int e = E_P2 + gtid; e < N_EDGES; e += NTHREADS) {
        int s = src[e], d = dst[e];
        int slot = atomicAdd(&cnt[d], 1);
        if (slot < DEG_CAP) bucket[(size_t)d * DEG_CAP + slot] = (unsigned short)s;
    }

    gg.sync();

    // ---------------- P4: gather — wave per node, shfl-broadcast weights ----------------
    {
        const unsigned int* oxh2 = (const unsigned int*)oxh;
        for (int n = wave_gid; n < N_NODES; n += NWAVES) {
            int deg = cnt[n];
            if (deg > DEG_CAP) deg = DEG_CAP;
            const unsigned short* row = bucket + (size_t)n * DEG_CAP;
            float ain = ai[n];

            float a = -INFINITY;
            int s = n;
            if (lane < deg) {
                s = row[lane];
                a = ain + aj[s];
                a = (a > 0.0f) ? a : 0.2f * a;
            } else if (lane == deg) {
                a = ain + aj[n];
                a = (a > 0.0f) ? a : 0.2f * a;
            }
            float mx = a;
            #pragma unroll
            for (int off = 32; off > 0; off >>= 1) mx = fmaxf(mx, __shfl_xor(mx, off, 64));
            float wgt = expf(a - mx);        // lanes > deg: exp(-inf) = 0
            float ssum = wgt;
            #pragma unroll
            for (int off = 32; off > 0; off >>= 1) ssum += __shfl_xor(ssum, off, 64);
            float wn = wgt / (ssum + 1e-16f);

            float wsf = __shfl(wn, deg, 64);           // self-loop weight
            unsigned int u = oxh2[(size_t)n * 64 + lane];
            float ax = wsf * bf2f_lo(u);
            float ay = wsf * bf2f_hi(u);
            for (int i = 0; i < deg; i++) {
                float wi = __shfl(wn, i, 64);
                int   si = __shfl(s, i, 64);
                unsigned int v = oxh2[(size_t)si * 64 + lane];
                ax += wi * bf2f_lo(v);
                ay += wi * bf2f_hi(v);
            }
            float2 o; o.x = ax; o.y = ay;
            *(float2*)(out + (size_t)n * DIM + lane * 2) = o;
        }
    }
}

extern "C" void kernel_launch(void* const* d_in, const int* in_sizes, int n_in,
                              void* d_out, int out_size, void* d_ws, size_t ws_size,
                              hipStream_t stream) {
    const float* x     = (const float*)d_in[0];
    const int*   ei    = (const int*)d_in[1];   // [2, E]
    const int*   label = (const int*)d_in[2];
    const float* W     = (const float*)d_in[3]; // [7, D, D]
    const float* att   = (const float*)d_in[4]; // [1, 1, 2D]
    float* out = (float*)d_out;

    const int* src = ei;
    const int* dst = ei + N_EDGES;

    // workspace (~19 MB)
    char* w = (char*)d_ws;
    unsigned short* oxh    = (unsigned short*)w; w += sizeof(unsigned short) * (size_t)N_NODES * DIM;
    unsigned short* Wt     = (unsigned short*)w; w += sizeof(unsigned short) * 7 * DIM * DIM;
    unsigned short* bucket = (unsigned short*)w; w += sizeof(unsigned short) * (size_t)N_NODES * DEG_CAP;
    float* ai        = (float*)w;  w += sizeof(float) * N_NODES;
    float* aj        = (float*)w;  w += sizeof(float) * N_NODES;
    int*   cnt       = (int*)w;    w += sizeof(int) * N_NODES;
    int*   node_list = (int*)w;    w += sizeof(int) * N_NODES;
    int*   lab_part  = (int*)w;    w += sizeof(int) * GRID * 8;
    int*   lab_off   = (int*)w;    w += sizeof(int) * 9;
    int*   lab_cur   = (int*)w;    w += sizeof(int) * 8;

    void* args[] = {&x, &src, &dst, &label, &W, &att, &out,
                    &oxh, &Wt, &bucket, &ai, &aj, &cnt, &node_list,
                    &lab_part, &lab_off, &lab_cur};
    hipLaunchCooperativeKernel((const void*)mega_kernel, dim3(GRID), dim3(BLOCK),
                               args, 0, stream);
}

// Round 10
// 192.238 us; speedup vs baseline: 2.9840x; 2.9840x over previous
//
#include <hip/hip_runtime.h>
#include <math.h>

#define N_NODES 50000
#define N_EDGES 800000
#define DIM 128
#define SCAN_BLOCKS ((N_NODES + 255) / 256)   // 196
#define NT_MAX (N_NODES / 16 + 8)             // 3133 tiles cover all 8 buckets
#define DEG_CAP 48                            // max deg ~ Poisson(16); far tail ~1e-10/node
#define BINS ((N_NODES + 255) / 256)          // 196 dst-bins of 256 nodes
#define BIN_CAP 8192                          // mean 4082 edges/bin; 8192 is >50 sd
#define EA_CHUNK 4096                         // edges per pass-A block

typedef __attribute__((ext_vector_type(8))) short short8;
typedef __attribute__((ext_vector_type(4))) float floatx4;

__device__ __forceinline__ unsigned short f2bf(float f) {
    unsigned int u = __float_as_uint(f);
    unsigned int r = (u + 0x7fff + ((u >> 16) & 1)) >> 16;  // RNE
    return (unsigned short)r;
}
__device__ __forceinline__ float bf2f_lo(unsigned int v) { return __uint_as_float(v << 16); }
__device__ __forceinline__ float bf2f_hi(unsigned int v) { return __uint_as_float(v & 0xffff0000u); }

// per-block label histogram -> lab_cnt (pre-zeroed by memset).
__global__ void init_kernel(const int* __restrict__ label,
                            int* __restrict__ lab_cnt) {
    __shared__ int lcnt[8];
    int t = threadIdx.x;
    int i = blockIdx.x * 256 + t;
    if (t < 8) lcnt[t] = 0;
    __syncthreads();
    if (i < N_NODES) {
        int lab = label[i];
        int b = (lab >= 1 && lab <= 7) ? (lab - 1) : 7;
        atomicAdd(&lcnt[b], 1);
    }
    __syncthreads();
    if (t < 8 && lcnt[t] > 0) atomicAdd(&lab_cnt[t], lcnt[t]);
}

__global__ void lab_scan_kernel(const int* __restrict__ lab_cnt,
                                int* __restrict__ lab_off,
                                int* __restrict__ lab_cur) {
    if (threadIdx.x == 0) {
        int a = 0;
        for (int i = 0; i < 8; i++) { lab_off[i] = a; lab_cur[i] = a; a += lab_cnt[i]; }
        lab_off[8] = a;
    }
}

// bucket nodes by label
__global__ void bucket_fill_kernel(const int* __restrict__ label,
                                   int* __restrict__ lab_cur,
                                   int* __restrict__ node_list) {
    __shared__ int lcnt[8], lbase[8], lrank[8];
    int t = threadIdx.x;
    int i = blockIdx.x * 256 + t;
    if (t < 8) { lcnt[t] = 0; lrank[t] = 0; }
    __syncthreads();
    int b = -1;
    if (i < N_NODES) {
        int lab = label[i];
        b = (lab >= 1 && lab <= 7) ? (lab - 1) : 7;
        atomicAdd(&lcnt[b], 1);
    }
    __syncthreads();
    if (t < 8) lbase[t] = (lcnt[t] > 0) ? atomicAdd(&lab_cur[t], lcnt[t]) : 0;
    __syncthreads();
    if (i < N_NODES) {
        int r = atomicAdd(&lrank[b], 1);
        node_list[lbase[b] + r] = i;
    }
}

// merged prep: x -> bf16 (into oxh) AND W -> W^T bf16
__global__ void prep_kernel(const float4* __restrict__ x4, ushort* __restrict__ xh,
                            const float* __restrict__ W, ushort* __restrict__ Wt) {
    int i = blockIdx.x * 256 + threadIdx.x;
    const int nx = N_NODES * DIM / 4;      // 1,600,000
    if (i < nx) {
        float4 v = x4[i];
        ushort4 o;
        o.x = f2bf(v.x); o.y = f2bf(v.y); o.z = f2bf(v.z); o.w = f2bf(v.w);
        ((ushort4*)xh)[i] = o;
    } else {
        int j = i - nx;
        if (j < 7 * DIM * DIM) {
            int b = j >> 14;
            int d = (j >> 7) & 127;
            int c = j & 127;
            Wt[((size_t)b * DIM + c) * DIM + d] = f2bf(W[j]);
        }
    }
}

// MFMA transform: one wave per 16-node tile of one bucket (4 tiles per 256-thread block).
__global__ __launch_bounds__(256) void transform_mfma_kernel(
        const ushort* __restrict__ xh, const float* __restrict__ x,
        const int* __restrict__ node_list, const int* __restrict__ lab_off,
        const ushort* __restrict__ Wt, const float* __restrict__ att,
        ushort* __restrict__ oxh, float* __restrict__ ai, float* __restrict__ aj) {
    int wv = threadIdx.x >> 6;
    int lane = threadIdx.x & 63;
    int tile = blockIdx.x * 4 + wv;

    int b = 0, base = 0, cnt = 0;
    for (; b < 8; b++) {
        int c0 = lab_off[b], c1 = lab_off[b + 1];
        int nt = (c1 - c0 + 15) >> 4;
        if (tile < nt) { base = c0 + tile * 16; cnt = c1 - base; break; }
        tile -= nt;
    }
    if (b == 8) return;
    if (cnt > 16) cnt = 16;

    int m = lane & 15;
    int quad = lane >> 4;

    floatx4 acc[8];
    #pragma unroll
    for (int nt = 0; nt < 8; nt++) acc[nt] = (floatx4){0.f, 0.f, 0.f, 0.f};

    if (b < 7) {
        int mm = (m < cnt) ? m : 0;
        int nodeA = node_list[base + mm];
        const ushort* xrow = xh + (size_t)nodeA * DIM;
        short8 afrag[4];
        #pragma unroll
        for (int kk = 0; kk < 4; kk++)
            afrag[kk] = *(const short8*)(xrow + kk * 32 + quad * 8);

        const ushort* WtB = Wt + (size_t)b * DIM * DIM;
        #pragma unroll
        for (int kk = 0; kk < 4; kk++) {
            #pragma unroll
            for (int nt = 0; nt < 8; nt++) {
                short8 bfrag = *(const short8*)(WtB + (size_t)(nt * 16 + m) * DIM + kk * 32 + quad * 8);
                acc[nt] = __builtin_amdgcn_mfma_f32_16x16x32_bf16(afrag[kk], bfrag, acc[nt], 0, 0, 0);
            }
        }
    }

    int nodes[4];
    #pragma unroll
    for (int r = 0; r < 4; r++) {
        int rw = quad * 4 + r;
        nodes[r] = node_list[base + ((rw < cnt) ? rw : 0)];
    }
    float pi[4] = {0.f, 0.f, 0.f, 0.f};
    float pj[4] = {0.f, 0.f, 0.f, 0.f};
    #pragma unroll
    for (int nt = 0; nt < 8; nt++) {
        int c = nt * 16 + m;
        float a1 = att[c];
        float a2 = att[DIM + c];
        #pragma unroll
        for (int r = 0; r < 4; r++) {
            int rw = quad * 4 + r;
            if (rw < cnt) {
                float xv = x[(size_t)nodes[r] * DIM + c];
                float v = (b < 7) ? (acc[nt][r] + xv) : xv;
                oxh[(size_t)nodes[r] * DIM + c] = f2bf(v);
                pi[r] += v * a1;
                pj[r] += v * a2;
            }
        }
    }
    #pragma unroll
    for (int r = 0; r < 4; r++) {
        #pragma unroll
        for (int off = 1; off < 16; off <<= 1) {
            pi[r] += __shfl_xor(pi[r], off, 64);
            pj[r] += __shfl_xor(pj[r], off, 64);
        }
        int rw = quad * 4 + r;
        if (m == 0 && rw < cnt) {
            ai[nodes[r]] = pi[r];
            aj[nodes[r]] = pj[r];
        }
    }
}

// Pass A: bin edges by dst>>8. One LDS histogram + one global reservation atomic
// per (block,bin); packed (dstlow<<16 | src) scattered into bin-local regions.
__global__ void binA_kernel(const int* __restrict__ src,
                            const int* __restrict__ dst,
                            int* __restrict__ bin_cur,
                            unsigned int* __restrict__ binned) {
    __shared__ int hist[BINS], base_s[BINS], rank[BINS];
    int t = threadIdx.x;
    for (int i = t; i < BINS; i += 256) { hist[i] = 0; rank[i] = 0; }
    __syncthreads();
    int e0 = blockIdx.x * EA_CHUNK;
    int e1 = e0 + EA_CHUNK; if (e1 > N_EDGES) e1 = N_EDGES;
    for (int e = e0 + t; e < e1; e += 256) {
        atomicAdd(&hist[dst[e] >> 8], 1);          // LDS atomic
    }
    __syncthreads();
    for (int i = t; i < BINS; i += 256) {
        base_s[i] = (hist[i] > 0) ? atomicAdd(&bin_cur[i], hist[i]) : 0;
    }
    __syncthreads();
    for (int e = e0 + t; e < e1; e += 256) {
        int d = dst[e];
        int b = d >> 8;
        int r = atomicAdd(&rank[b], 1);            // LDS atomic
        int slot = base_s[b] + r;
        if (slot < BIN_CAP)
            binned[(size_t)b * BIN_CAP + slot] = (unsigned int)(src[e] | ((d & 255) << 16));
    }
}

// Pass B: one block per bin. LDS counting-sort by low-8 dst bits; write cnt + bucket
// rows for 256 nodes into a contiguous region. No global atomics.
__global__ void binB_kernel(const int* __restrict__ bin_cur,
                            const unsigned int* __restrict__ binned,
                            int* __restrict__ cnt,
                            unsigned short* __restrict__ bucket) {
    __shared__ int hist[256], off[256], cur[256], sc[256];
    __shared__ unsigned short srt[BIN_CAP];   // 16 KB
    int b = blockIdx.x;
    int t = threadIdx.x;
    int m = bin_cur[b]; if (m > BIN_CAP) m = BIN_CAP;
    const unsigned int* bp = binned + (size_t)b * BIN_CAP;

    hist[t] = 0; cur[t] = 0;
    __syncthreads();
    for (int i = t; i < m; i += 256) {
        atomicAdd(&hist[(bp[i] >> 16) & 255], 1);  // LDS atomic
    }
    __syncthreads();
    sc[t] = hist[t];
    __syncthreads();
    #pragma unroll
    for (int d = 1; d < 256; d <<= 1) {
        int add = (t >= d) ? sc[t - d] : 0;
        __syncthreads();
        sc[t] += add;
        __syncthreads();
    }
    off[t] = sc[t] - hist[t];
    __syncthreads();
    for (int i = t; i < m; i += 256) {
        unsigned int v = bp[i];
        int ln = (v >> 16) & 255;
        int r = atomicAdd(&cur[ln], 1);            // LDS atomic
        srt[off[ln] + r] = (unsigned short)(v & 0xFFFF);
    }
    __syncthreads();
    int n = b * 256 + t;
    if (n < N_NODES) {
        int deg = hist[t];
        if (deg > DEG_CAP) deg = DEG_CAP;
        cnt[n] = deg;
        int o = off[t];
        unsigned short* brow = bucket + (size_t)n * DEG_CAP;
        for (int k = 0; k < deg; k++) brow[k] = srt[o + k];
    }
}

// One wave (64 threads) per node. Phase 1 (lane-per-edge): softmax weights -> LDS.
// Phase 2 (lane-per-2-columns): out[n] = w_self*oxh[n] + sum_i w_i*oxh[src_i].
__global__ void gather4_kernel(const int* __restrict__ cnt,
                               const unsigned short* __restrict__ bucket,
                               const float* __restrict__ ai,
                               const float* __restrict__ aj,
                               const unsigned int* __restrict__ oxh2,
                               float* __restrict__ out) {
    int n = blockIdx.x;
    int lane = threadIdx.x;  // 0..63
    __shared__ float wl[64];
    __shared__ int   sl[64];
    int deg = cnt[n];
    if (deg > DEG_CAP) deg = DEG_CAP;
    const unsigned short* row = bucket + (size_t)n * DEG_CAP;
    float ain = ai[n];

    float a = -INFINITY;
    int s = n;
    if (lane < deg) {
        s = row[lane];
        a = ain + aj[s];
        a = (a > 0.0f) ? a : 0.2f * a;
    } else if (lane == deg) {
        a = ain + aj[n];
        a = (a > 0.0f) ? a : 0.2f * a;
    }
    float mx = a;
    #pragma unroll
    for (int off = 32; off > 0; off >>= 1) mx = fmaxf(mx, __shfl_xor(mx, off, 64));
    float w = expf(a - mx);              // lanes > deg: exp(-inf) = 0
    float ssum = w;
    #pragma unroll
    for (int off = 32; off > 0; off >>= 1) ssum += __shfl_xor(ssum, off, 64);
    float inv = 1.0f / (ssum + 1e-16f);
    wl[lane] = w * inv;
    sl[lane] = s;
    __syncthreads();

    float wsf = wl[deg];                 // self-loop weight (lane==deg wrote it)
    unsigned int u = oxh2[(size_t)n * 64 + lane];
    float ax = wsf * bf2f_lo(u);
    float ay = wsf * bf2f_hi(u);

    int i = 0;
    for (; i + 1 < deg; i += 2) {
        int s0 = sl[i],   s1 = sl[i + 1];
        float w0 = wl[i], w1 = wl[i + 1];
        unsigned int v0 = oxh2[(size_t)s0 * 64 + lane];
        unsigned int v1 = oxh2[(size_t)s1 * 64 + lane];
        ax += w0 * bf2f_lo(v0) + w1 * bf2f_lo(v1);
        ay += w0 * bf2f_hi(v0) + w1 * bf2f_hi(v1);
    }
    if (i < deg) {
        int s0 = sl[i];
        float w0 = wl[i];
        unsigned int v0 = oxh2[(size_t)s0 * 64 + lane];
        ax += w0 * bf2f_lo(v0);
        ay += w0 * bf2f_hi(v0);
    }
    float2 o; o.x = ax; o.y = ay;
    *(float2*)(out + (size_t)n * DIM + lane * 2) = o;
}

extern "C" void kernel_launch(void* const* d_in, const int* in_sizes, int n_in,
                              void* d_out, int out_size, void* d_ws, size_t ws_size,
                              hipStream_t stream) {
    const float* x     = (const float*)d_in[0];
    const int*   ei    = (const int*)d_in[1];   // [2, E]
    const int*   label = (const int*)d_in[2];
    const float* W     = (const float*)d_in[3]; // [7, D, D]
    const float* att   = (const float*)d_in[4]; // [1, 1, 2D]
    float* out = (float*)d_out;

    const int* src = ei;
    const int* dst = ei + N_EDGES;

    // workspace (~26 MB). oxh doubles as xh (in-place tile overwrite, wave-local).
    char* w = (char*)d_ws;
    unsigned short* oxh    = (unsigned short*)w; w += sizeof(unsigned short) * (size_t)N_NODES * DIM;
    unsigned short* Wt     = (unsigned short*)w; w += sizeof(unsigned short) * 7 * DIM * DIM;
    unsigned short* bucket = (unsigned short*)w; w += sizeof(unsigned short) * (size_t)N_NODES * DEG_CAP;
    unsigned int*   binned = (unsigned int*)w;   w += sizeof(unsigned int) * (size_t)BINS * BIN_CAP;
    float* ai        = (float*)w;  w += sizeof(float) * N_NODES;
    float* aj        = (float*)w;  w += sizeof(float) * N_NODES;
    int*   cnt       = (int*)w;    w += sizeof(int) * N_NODES;
    int*   node_list = (int*)w;    w += sizeof(int) * N_NODES;
    // zero-region: lab_cnt(8) + bin_cur(BINS) contiguous, one memset
    int*   lab_cnt   = (int*)w;    w += sizeof(int) * 8;
    int*   bin_cur   = (int*)w;    w += sizeof(int) * BINS;
    int*   lab_off   = (int*)w;    w += sizeof(int) * 9;
    int*   lab_cur   = (int*)w;    w += sizeof(int) * 8;

    hipMemsetAsync(lab_cnt, 0, sizeof(int) * (8 + BINS), stream);

    init_kernel<<<SCAN_BLOCKS, 256, 0, stream>>>(label, lab_cnt);

    lab_scan_kernel<<<1, 64, 0, stream>>>(lab_cnt, lab_off, lab_cur);

    bucket_fill_kernel<<<SCAN_BLOCKS, 256, 0, stream>>>(label, lab_cur, node_list);

    int prep_total = N_NODES * DIM / 4 + 7 * DIM * DIM;
    prep_kernel<<<(prep_total + 255) / 256, 256, 0, stream>>>((const float4*)x, oxh, W, Wt);

    transform_mfma_kernel<<<(NT_MAX + 3) / 4, 256, 0, stream>>>(
        oxh, x, node_list, lab_off, Wt, att, oxh, ai, aj);

    binA_kernel<<<(N_EDGES + EA_CHUNK - 1) / EA_CHUNK, 256, 0, stream>>>(src, dst, bin_cur, binned);

    binB_kernel<<<BINS, 256, 0, stream>>>(bin_cur, binned, cnt, bucket);

    gather4_kernel<<<N_NODES, 64, 0, stream>>>(cnt, bucket, ai, aj,
                                               (const unsigned int*)oxh, out);
}

// Round 11
// 171.184 us; speedup vs baseline: 3.3510x; 1.1230x over previous
//
#include <hip/hip_runtime.h>
#include <math.h>

#define N_NODES 50000
#define N_EDGES 800000
#define DIM 128
#define SCAN_BLOCKS ((N_NODES + 255) / 256)   // 196 node-chunks
#define DEG_CAP 48                            // max deg ~ Poisson(16); far tail ~1e-10/node
#define BINS ((N_NODES + 255) / 256)          // 196 dst-bins of 256 nodes
#define BIN_CAP 8192                          // mean 4082 edges/bin; 8192 is >50 sd
#define EA_CHUNK 4096                         // edges per binA block

#define PREP_ELEMS (N_NODES * DIM / 4 + 7 * DIM * DIM)   // 1,714,688
#define PREP_BLOCKS ((PREP_ELEMS + 255) / 256)           // 6699
#define P1_GRID (BINS + PREP_BLOCKS + SCAN_BLOCKS)       // 7091

#define TR_BLOCKS 784                         // 3136 tile-waves >= 3133 max tiles
#define P2_GRID (BINS + TR_BLOCKS)            // 980

typedef __attribute__((ext_vector_type(8))) short short8;
typedef __attribute__((ext_vector_type(4))) float floatx4;

__device__ __forceinline__ unsigned short f2bf(float f) {
    unsigned int u = __float_as_uint(f);
    unsigned int r = (u + 0x7fff + ((u >> 16) & 1)) >> 16;  // RNE
    return (unsigned short)r;
}
__device__ __forceinline__ float bf2f_lo(unsigned int v) { return __uint_as_float(v << 16); }
__device__ __forceinline__ float bf2f_hi(unsigned int v) { return __uint_as_float(v & 0xffff0000u); }

// ---------------- Phase 1: binA | prep(xh+Wt) | label-bucket (all input-only) ----------------
__global__ __launch_bounds__(256) void phase1_kernel(
        const float* __restrict__ x, const int* __restrict__ src, const int* __restrict__ dst,
        const int* __restrict__ label, const float* __restrict__ W,
        unsigned short* __restrict__ oxh, unsigned short* __restrict__ Wt,
        int* __restrict__ bin_cur, unsigned int* __restrict__ binned,
        int* __restrict__ lab_cnt, int* __restrict__ node_list) {
    int t = threadIdx.x;
    int blk = blockIdx.x;

    if (blk < BINS) {
        // --- binA: bin edges by dst>>8; LDS histogram + 1 global reservation per bin ---
        __shared__ int hist[BINS], base_s[BINS], rank[BINS];
        for (int i = t; i < BINS; i += 256) { hist[i] = 0; rank[i] = 0; }
        __syncthreads();
        int e0 = blk * EA_CHUNK;
        int e1 = e0 + EA_CHUNK; if (e1 > N_EDGES) e1 = N_EDGES;
        for (int e = e0 + t; e < e1; e += 256) atomicAdd(&hist[dst[e] >> 8], 1);
        __syncthreads();
        for (int i = t; i < BINS; i += 256)
            base_s[i] = (hist[i] > 0) ? atomicAdd(&bin_cur[i], hist[i]) : 0;
        __syncthreads();
        for (int e = e0 + t; e < e1; e += 256) {
            int d = dst[e];
            int b = d >> 8;
            int r = atomicAdd(&rank[b], 1);
            int slot = base_s[b] + r;
            if (slot < BIN_CAP)
                binned[(size_t)b * BIN_CAP + slot] = (unsigned int)(src[e] | ((d & 255) << 16));
        }
    } else if (blk < BINS + PREP_BLOCKS) {
        // --- prep: x -> bf16 xh (into oxh); W -> W^T bf16 ---
        int i = (blk - BINS) * 256 + t;
        const int nx = N_NODES * DIM / 4;
        if (i < nx) {
            float4 v = ((const float4*)x)[i];
            ushort4 o;
            o.x = f2bf(v.x); o.y = f2bf(v.y); o.z = f2bf(v.z); o.w = f2bf(v.w);
            ((ushort4*)oxh)[i] = o;
        } else {
            int j = i - nx;
            if (j < 7 * DIM * DIM) {
                int b = j >> 14;
                int d = (j >> 7) & 127;
                int c = j & 127;
                Wt[((size_t)b * DIM + c) * DIM + d] = f2bf(W[j]);
            }
        }
    } else {
        // --- one-pass label bucketing into fixed per-label regions node_list[b*N ..] ---
        __shared__ int lcnt[8], lbase[8], lrank[8];
        int i = (blk - BINS - PREP_BLOCKS) * 256 + t;
        if (t < 8) { lcnt[t] = 0; lrank[t] = 0; }
        __syncthreads();
        int b = -1;
        if (i < N_NODES) {
            int lab = label[i];
            b = (lab >= 1 && lab <= 7) ? (lab - 1) : 7;
            atomicAdd(&lcnt[b], 1);
        }
        __syncthreads();
        if (t < 8) lbase[t] = (lcnt[t] > 0) ? atomicAdd(&lab_cnt[t], lcnt[t]) : 0;
        __syncthreads();
        if (i < N_NODES) {
            int r = atomicAdd(&lrank[b], 1);
            node_list[(size_t)b * N_NODES + lbase[b] + r] = i;
        }
    }
}

// ---------------- Phase 2: binB | MFMA transform (independent of each other) ----------------
__global__ __launch_bounds__(256) void phase2_kernel(
        const float* __restrict__ x, const float* __restrict__ att,
        const int* __restrict__ lab_cnt, const int* __restrict__ node_list,
        const unsigned short* __restrict__ Wt,
        const int* __restrict__ bin_cur, const unsigned int* __restrict__ binned,
        unsigned short* __restrict__ oxh, float* __restrict__ ai, float* __restrict__ aj,
        int* __restrict__ cnt, unsigned short* __restrict__ bucket) {
    int t = threadIdx.x;
    int blk = blockIdx.x;

    if (blk < BINS) {
        // --- binB: counting-sort one bin by low-8 dst bits; write cnt + bucket rows ---
        __shared__ int hist[256], off[256], cur[256], sc[256];
        __shared__ unsigned short srt[BIN_CAP];   // 16 KB
        int b = blk;
        int m = bin_cur[b]; if (m > BIN_CAP) m = BIN_CAP;
        const unsigned int* bp = binned + (size_t)b * BIN_CAP;

        hist[t] = 0; cur[t] = 0;
        __syncthreads();
        for (int i = t; i < m; i += 256) atomicAdd(&hist[(bp[i] >> 16) & 255], 1);
        __syncthreads();
        sc[t] = hist[t];
        __syncthreads();
        #pragma unroll
        for (int d = 1; d < 256; d <<= 1) {
            int add = (t >= d) ? sc[t - d] : 0;
            __syncthreads();
            sc[t] += add;
            __syncthreads();
        }
        off[t] = sc[t] - hist[t];
        __syncthreads();
        for (int i = t; i < m; i += 256) {
            unsigned int v = bp[i];
            int ln = (v >> 16) & 255;
            int r = atomicAdd(&cur[ln], 1);
            srt[off[ln] + r] = (unsigned short)(v & 0xFFFF);
        }
        __syncthreads();
        int n = b * 256 + t;
        if (n < N_NODES) {
            int deg = hist[t];
            if (deg > DEG_CAP) deg = DEG_CAP;
            cnt[n] = deg;
            int o = off[t];
            unsigned short* brow = bucket + (size_t)n * DEG_CAP;
            for (int k = 0; k < deg; k++) brow[k] = srt[o + k];
        }
    } else {
        // --- MFMA transform: wave per 16-node tile ---
        int wv = t >> 6;
        int lane = t & 63;
        int tile = (blk - BINS) * 4 + wv;

        int b = 0, base = 0, tcnt = 0;
        for (; b < 8; b++) {
            int c = lab_cnt[b];
            int nt = (c + 15) >> 4;
            if (tile < nt) { base = b * N_NODES + tile * 16; tcnt = c - tile * 16; break; }
            tile -= nt;
        }
        if (b == 8) return;
        if (tcnt > 16) tcnt = 16;

        int m = lane & 15;
        int quad = lane >> 4;

        floatx4 acc[8];
        #pragma unroll
        for (int nt = 0; nt < 8; nt++) acc[nt] = (floatx4){0.f, 0.f, 0.f, 0.f};

        if (b < 7) {
            int mm = (m < tcnt) ? m : 0;
            int nodeA = node_list[base + mm];
            const unsigned short* xrow = oxh + (size_t)nodeA * DIM;
            short8 afrag[4];
            #pragma unroll
            for (int kk = 0; kk < 4; kk++)
                afrag[kk] = *(const short8*)(xrow + kk * 32 + quad * 8);

            const unsigned short* WtB = Wt + (size_t)b * DIM * DIM;
            #pragma unroll
            for (int kk = 0; kk < 4; kk++) {
                #pragma unroll
                for (int nt = 0; nt < 8; nt++) {
                    short8 bfrag = *(const short8*)(WtB + (size_t)(nt * 16 + m) * DIM + kk * 32 + quad * 8);
                    acc[nt] = __builtin_amdgcn_mfma_f32_16x16x32_bf16(afrag[kk], bfrag, acc[nt], 0, 0, 0);
                }
            }
        }

        int nodes[4];
        #pragma unroll
        for (int r = 0; r < 4; r++) {
            int rw = quad * 4 + r;
            nodes[r] = node_list[base + ((rw < tcnt) ? rw : 0)];
        }
        float pi[4] = {0.f, 0.f, 0.f, 0.f};
        float pj[4] = {0.f, 0.f, 0.f, 0.f};
        #pragma unroll
        for (int nt = 0; nt < 8; nt++) {
            int c = nt * 16 + m;
            float a1 = att[c];
            float a2 = att[DIM + c];
            #pragma unroll
            for (int r = 0; r < 4; r++) {
                int rw = quad * 4 + r;
                if (rw < tcnt) {
                    float xv = x[(size_t)nodes[r] * DIM + c];
                    float v = (b < 7) ? (acc[nt][r] + xv) : xv;
                    if (b < 7) oxh[(size_t)nodes[r] * DIM + c] = f2bf(v);  // identity rows already correct
                    pi[r] += v * a1;
                    pj[r] += v * a2;
                }
            }
        }
        #pragma unroll
        for (int r = 0; r < 4; r++) {
            #pragma unroll
            for (int off = 1; off < 16; off <<= 1) {
                pi[r] += __shfl_xor(pi[r], off, 64);
                pj[r] += __shfl_xor(pj[r], off, 64);
            }
            int rw = quad * 4 + r;
            if (m == 0 && rw < tcnt) {
                ai[nodes[r]] = pi[r];
                aj[nodes[r]] = pj[r];
            }
        }
    }
}

// ---------------- Gather: wave per node (4/block), shfl-broadcast weights ----------------
__global__ __launch_bounds__(256) void gather5_kernel(
        const int* __restrict__ cnt, const unsigned short* __restrict__ bucket,
        const float* __restrict__ ai, const float* __restrict__ aj,
        const unsigned int* __restrict__ oxh2, float* __restrict__ out) {
    int wv = threadIdx.x >> 6;
    int lane = threadIdx.x & 63;
    int n = blockIdx.x * 4 + wv;          // grid covers exactly N_NODES
    if (n >= N_NODES) return;
    int deg = cnt[n];
    if (deg > DEG_CAP) deg = DEG_CAP;
    const unsigned short* row = bucket + (size_t)n * DEG_CAP;
    float ain = ai[n];

    float a = -INFINITY;
    int s = n;
    if (lane < deg) {
        s = row[lane];
        a = ain + aj[s];
        a = (a > 0.0f) ? a : 0.2f * a;
    } else if (lane == deg) {
        a = ain + aj[n];
        a = (a > 0.0f) ? a : 0.2f * a;
    }
    float mx = a;
    #pragma unroll
    for (int off = 32; off > 0; off >>= 1) mx = fmaxf(mx, __shfl_xor(mx, off, 64));
    float w = expf(a - mx);              // lanes > deg: exp(-inf) = 0
    float ssum = w;
    #pragma unroll
    for (int off = 32; off > 0; off >>= 1) ssum += __shfl_xor(ssum, off, 64);
    float wn = w / (ssum + 1e-16f);

    float wsf = __shfl(wn, deg, 64);     // self-loop weight
    unsigned int u = oxh2[(size_t)n * 64 + lane];
    float ax = wsf * bf2f_lo(u);
    float ay = wsf * bf2f_hi(u);

    int i = 0;
    for (; i + 1 < deg; i += 2) {
        float w0 = __shfl(wn, i, 64),     w1 = __shfl(wn, i + 1, 64);
        int   s0 = __shfl(s, i, 64),      s1 = __shfl(s, i + 1, 64);
        unsigned int v0 = oxh2[(size_t)s0 * 64 + lane];
        unsigned int v1 = oxh2[(size_t)s1 * 64 + lane];
        ax += w0 * bf2f_lo(v0) + w1 * bf2f_lo(v1);
        ay += w0 * bf2f_hi(v0) + w1 * bf2f_hi(v1);
    }
    if (i < deg) {
        float w0 = __shfl(wn, i, 64);
        int   s0 = __shfl(s, i, 64);
        unsigned int v0 = oxh2[(size_t)s0 * 64 + lane];
        ax += w0 * bf2f_lo(v0);
        ay += w0 * bf2f_hi(v0);
    }
    float2 o; o.x = ax; o.y = ay;
    *(float2*)(out + (size_t)n * DIM + lane * 2) = o;
}

extern "C" void kernel_launch(void* const* d_in, const int* in_sizes, int n_in,
                              void* d_out, int out_size, void* d_ws, size_t ws_size,
                              hipStream_t stream) {
    const float* x     = (const float*)d_in[0];
    const int*   ei    = (const int*)d_in[1];   // [2, E]
    const int*   label = (const int*)d_in[2];
    const float* W     = (const float*)d_in[3]; // [7, D, D]
    const float* att   = (const float*)d_in[4]; // [1, 1, 2D]
    float* out = (float*)d_out;

    const int* src = ei;
    const int* dst = ei + N_EDGES;

    // workspace (~27 MB). oxh doubles as xh (in-place tile overwrite, wave-local).
    char* w = (char*)d_ws;
    unsigned short* oxh    = (unsigned short*)w; w += sizeof(unsigned short) * (size_t)N_NODES * DIM;
    unsigned short* Wt     = (unsigned short*)w; w += sizeof(unsigned short) * 7 * DIM * DIM;
    unsigned short* bucket = (unsigned short*)w; w += sizeof(unsigned short) * (size_t)N_NODES * DEG_CAP;
    unsigned int*   binned = (unsigned int*)w;   w += sizeof(unsigned int) * (size_t)BINS * BIN_CAP;
    float* ai        = (float*)w;  w += sizeof(float) * N_NODES;
    float* aj        = (float*)w;  w += sizeof(float) * N_NODES;
    int*   cnt       = (int*)w;    w += sizeof(int) * N_NODES;
    int*   node_list = (int*)w;    w += sizeof(int) * (size_t)8 * N_NODES;
    // zero-region: lab_cnt(8) + bin_cur(BINS) contiguous, one memset
    int*   lab_cnt   = (int*)w;    w += sizeof(int) * 8;
    int*   bin_cur   = (int*)w;    w += sizeof(int) * BINS;

    hipMemsetAsync(lab_cnt, 0, sizeof(int) * (8 + BINS), stream);

    phase1_kernel<<<P1_GRID, 256, 0, stream>>>(x, src, dst, label, W,
                                               oxh, Wt, bin_cur, binned, lab_cnt, node_list);

    phase2_kernel<<<P2_GRID, 256, 0, stream>>>(x, att, lab_cnt, node_list, Wt,
                                               bin_cur, binned, oxh, ai, aj, cnt, bucket);

    gather5_kernel<<<(N_NODES + 3) / 4, 256, 0, stream>>>(cnt, bucket, ai, aj,
                                                          (const unsigned int*)oxh, out);
}

// Round 13
// 166.425 us; speedup vs baseline: 3.4469x; 1.0286x over previous
//
#include <hip/hip_runtime.h>
#include <math.h>

#define N_NODES 50000
#define N_EDGES 800000
#define DIM 128
#define SCAN_BLOCKS ((N_NODES + 255) / 256)   // 196 node-chunks
#define DEG_CAP 48                            // max deg ~ Poisson(16); far tail ~1e-10/node
#define BINS ((N_NODES + 255) / 256)          // 196 dst-bins of 256 nodes
#define BIN_CAP 8192                          // mean 4082 edges/bin; 8192 is >50 sd
#define EA_CHUNK 4096                         // edges per binA block

#define PREP_ELEMS (N_NODES * DIM / 4 + 7 * DIM * DIM)   // 1,714,688
#define PREP_BLOCKS ((PREP_ELEMS + 255) / 256)           // 6699
#define P1_GRID (BINS + PREP_BLOCKS + SCAN_BLOCKS)       // 7091

#define TR_BLOCKS 784                         // 3136 tile-waves >= 3133 max tiles
#define P2_GRID (BINS + TR_BLOCKS)            // 980

typedef __attribute__((ext_vector_type(8))) short short8;
typedef __attribute__((ext_vector_type(4))) float floatx4;

__device__ __forceinline__ unsigned short f2bf(float f) {
    unsigned int u = __float_as_uint(f);
    unsigned int r = (u + 0x7fff + ((u >> 16) & 1)) >> 16;  // RNE
    return (unsigned short)r;
}
__device__ __forceinline__ float bf2f_lo(unsigned int v) { return __uint_as_float(v << 16); }
__device__ __forceinline__ float bf2f_hi(unsigned int v) { return __uint_as_float(v & 0xffff0000u); }

// ---------------- Phase 1: binA | prep(xh+Wt) | label-bucket (all input-only) ----------------
__global__ __launch_bounds__(256) void phase1_kernel(
        const float* __restrict__ x, const int* __restrict__ src, const int* __restrict__ dst,
        const int* __restrict__ label, const float* __restrict__ W,
        unsigned short* __restrict__ oxh, unsigned short* __restrict__ Wt,
        int* __restrict__ bin_cur, unsigned int* __restrict__ binned,
        int* __restrict__ lab_cnt, int* __restrict__ node_list) {
    int t = threadIdx.x;
    int blk = blockIdx.x;

    if (blk < BINS) {
        // --- binA: bin edges by dst>>8; LDS histogram + 1 global reservation per bin ---
        __shared__ int hist[BINS], base_s[BINS], rank[BINS];
        for (int i = t; i < BINS; i += 256) { hist[i] = 0; rank[i] = 0; }
        __syncthreads();
        int e0 = blk * EA_CHUNK;
        int e1 = e0 + EA_CHUNK; if (e1 > N_EDGES) e1 = N_EDGES;
        for (int e = e0 + t; e < e1; e += 256) atomicAdd(&hist[dst[e] >> 8], 1);
        __syncthreads();
        for (int i = t; i < BINS; i += 256)
            base_s[i] = (hist[i] > 0) ? atomicAdd(&bin_cur[i], hist[i]) : 0;
        __syncthreads();
        for (int e = e0 + t; e < e1; e += 256) {
            int d = dst[e];
            int b = d >> 8;
            int r = atomicAdd(&rank[b], 1);
            int slot = base_s[b] + r;
            if (slot < BIN_CAP)
                binned[(size_t)b * BIN_CAP + slot] = (unsigned int)(src[e] | ((d & 255) << 16));
        }
    } else if (blk < BINS + PREP_BLOCKS) {
        // --- prep: x -> bf16 xh (into oxh); W -> W^T bf16 ---
        int i = (blk - BINS) * 256 + t;
        const int nx = N_NODES * DIM / 4;
        if (i < nx) {
            float4 v = ((const float4*)x)[i];
            ushort4 o;
            o.x = f2bf(v.x); o.y = f2bf(v.y); o.z = f2bf(v.z); o.w = f2bf(v.w);
            ((ushort4*)oxh)[i] = o;
        } else {
            int j = i - nx;
            if (j < 7 * DIM * DIM) {
                int b = j >> 14;
                int d = (j >> 7) & 127;
                int c = j & 127;
                Wt[((size_t)b * DIM + c) * DIM + d] = f2bf(W[j]);
            }
        }
    } else {
        // --- one-pass label bucketing into fixed per-label regions node_list[b*N ..] ---
        __shared__ int lcnt[8], lbase[8], lrank[8];
        int i = (blk - BINS - PREP_BLOCKS) * 256 + t;
        if (t < 8) { lcnt[t] = 0; lrank[t] = 0; }
        __syncthreads();
        int b = -1;
        if (i < N_NODES) {
            int lab = label[i];
            b = (lab >= 1 && lab <= 7) ? (lab - 1) : 7;
            atomicAdd(&lcnt[b], 1);
        }
        __syncthreads();
        if (t < 8) lbase[t] = (lcnt[t] > 0) ? atomicAdd(&lab_cnt[t], lcnt[t]) : 0;
        __syncthreads();
        if (i < N_NODES) {
            int r = atomicAdd(&lrank[b], 1);
            node_list[(size_t)b * N_NODES + lbase[b] + r] = i;
        }
    }
}

// ---------------- Phase 2: binB | MFMA transform (independent of each other) ----------------
__global__ __launch_bounds__(256) void phase2_kernel(
        const float* __restrict__ x, const float* __restrict__ att,
        const int* __restrict__ lab_cnt, const int* __restrict__ node_list,
        const unsigned short* __restrict__ Wt,
        const int* __restrict__ bin_cur, const unsigned int* __restrict__ binned,
        unsigned short* __restrict__ oxh, float* __restrict__ ai, float* __restrict__ aj,
        int* __restrict__ cnt, unsigned short* __restrict__ bucket) {
    int t = threadIdx.x;
    int blk = blockIdx.x;

    if (blk < BINS) {
        // --- binB: counting-sort one bin by low-8 dst bits; write cnt + bucket rows ---
        __shared__ int hist[256], off[256], cur[256], sc[256];
        __shared__ unsigned short srt[BIN_CAP];   // 16 KB
        int b = blk;
        int m = bin_cur[b]; if (m > BIN_CAP) m = BIN_CAP;
        const unsigned int* bp = binned + (size_t)b * BIN_CAP;

        hist[t] = 0; cur[t] = 0;
        __syncthreads();
        for (int i = t; i < m; i += 256) atomicAdd(&hist[(bp[i] >> 16) & 255], 1);
        __syncthreads();
        sc[t] = hist[t];
        __syncthreads();
        #pragma unroll
        for (int d = 1; d < 256; d <<= 1) {
            int add = (t >= d) ? sc[t - d] : 0;
            __syncthreads();
            sc[t] += add;
            __syncthreads();
        }
        off[t] = sc[t] - hist[t];
        __syncthreads();
        for (int i = t; i < m; i += 256) {
            unsigned int v = bp[i];
            int ln = (v >> 16) & 255;
            int r = atomicAdd(&cur[ln], 1);
            srt[off[ln] + r] = (unsigned short)(v & 0xFFFF);
        }
        __syncthreads();
        int n = b * 256 + t;
        if (n < N_NODES) {
            int deg = hist[t];
            if (deg > DEG_CAP) deg = DEG_CAP;
            cnt[n] = deg;
            int o = off[t];
            unsigned short* brow = bucket + (size_t)n * DEG_CAP;
            for (int k = 0; k < deg; k++) brow[k] = srt[o + k];
        }
    } else {
        // --- MFMA transform: wave per 16-node tile ---
        int wv = t >> 6;
        int lane = t & 63;
        int tile = (blk - BINS) * 4 + wv;

        int b = 0, base = 0, tcnt = 0;
        for (; b < 8; b++) {
            int c = lab_cnt[b];
            int nt = (c + 15) >> 4;
            if (tile < nt) { base = b * N_NODES + tile * 16; tcnt = c - tile * 16; break; }
            tile -= nt;
        }
        if (b == 8) return;
        if (tcnt > 16) tcnt = 16;

        int m = lane & 15;
        int quad = lane >> 4;

        floatx4 acc[8];
        #pragma unroll
        for (int nt = 0; nt < 8; nt++) acc[nt] = (floatx4){0.f, 0.f, 0.f, 0.f};

        if (b < 7) {
            int mm = (m < tcnt) ? m : 0;
            int nodeA = node_list[base + mm];
            const unsigned short* xrow = oxh + (size_t)nodeA * DIM;
            short8 afrag[4];
            #pragma unroll
            for (int kk = 0; kk < 4; kk++)
                afrag[kk] = *(const short8*)(xrow + kk * 32 + quad * 8);

            const unsigned short* WtB = Wt + (size_t)b * DIM * DIM;
            #pragma unroll
            for (int kk = 0; kk < 4; kk++) {
                #pragma unroll
                for (int nt = 0; nt < 8; nt++) {
                    short8 bfrag = *(const short8*)(WtB + (size_t)(nt * 16 + m) * DIM + kk * 32 + quad * 8);
                    acc[nt] = __builtin_amdgcn_mfma_f32_16x16x32_bf16(afrag[kk], bfrag, acc[nt], 0, 0, 0);
                }
            }
        }

        int nodes[4];
        #pragma unroll
        for (int r = 0; r < 4; r++) {
            int rw = quad * 4 + r;
            nodes[r] = node_list[base + ((rw < tcnt) ? rw : 0)];
        }
        float pi[4] = {0.f, 0.f, 0.f, 0.f};
        float pj[4] = {0.f, 0.f, 0.f, 0.f};
        #pragma unroll
        for (int nt = 0; nt < 8; nt++) {
            int c = nt * 16 + m;
            float a1 = att[c];
            float a2 = att[DIM + c];
            #pragma unroll
            for (int r = 0; r < 4; r++) {
                int rw = quad * 4 + r;
                if (rw < tcnt) {
                    float xv = x[(size_t)nodes[r] * DIM + c];
                    float v = (b < 7) ? (acc[nt][r] + xv) : xv;
                    if (b < 7) oxh[(size_t)nodes[r] * DIM + c] = f2bf(v);  // identity rows already correct
                    pi[r] += v * a1;
                    pj[r] += v * a2;
                }
            }
        }
        #pragma unroll
        for (int r = 0; r < 4; r++) {
            #pragma unroll
            for (int off = 1; off < 16; off <<= 1) {
                pi[r] += __shfl_xor(pi[r], off, 64);
                pj[r] += __shfl_xor(pj[r], off, 64);
            }
            int rw = quad * 4 + r;
            if (m == 0 && rw < tcnt) {
                ai[nodes[r]] = pi[r];
                aj[nodes[r]] = pj[r];
            }
        }
    }
}

// ---------------- Gather: wave per node; 4x16-lane groups, dwordx4 loads ----------------
// Phase A (lane-per-edge): softmax weights wn in registers.
// Phase B: WAVE-UNIFORM loop of ceil(deg/4) iters; group g handles edge g+4k with
// shfl source CLAMPED to lane 0 (always active) and weight zeroed when g+4k >= deg.
// All 64 lanes stay converged at every __shfl (R12 bug: divergent tail made shfl
// read inactive lanes -> undefined data on AMD ds_bpermute).
__global__ __launch_bounds__(256) void gather6_kernel(
        const int* __restrict__ cnt, const unsigned short* __restrict__ bucket,
        const float* __restrict__ ai, const float* __restrict__ aj,
        const uint4* __restrict__ tab,     // oxh rows as 16 x uint4
        float* __restrict__ out) {
    int wv = threadIdx.x >> 6;
    int lane = threadIdx.x & 63;
    int n = blockIdx.x * 4 + wv;
    if (n >= N_NODES) return;
    int deg = cnt[n];
    if (deg > DEG_CAP) deg = DEG_CAP;
    const unsigned short* row = bucket + (size_t)n * DEG_CAP;
    float ain = ai[n];

    // phase A: lane i<deg = edge i; lane==deg = self loop; others weight 0
    float a = -INFINITY;
    int s = n;
    if (lane < deg) {
        s = row[lane];
        a = ain + aj[s];
        a = (a > 0.0f) ? a : 0.2f * a;
    } else if (lane == deg) {
        a = ain + aj[n];
        a = (a > 0.0f) ? a : 0.2f * a;
    }
    float mx = a;
    #pragma unroll
    for (int off = 32; off > 0; off >>= 1) mx = fmaxf(mx, __shfl_xor(mx, off, 64));
    float w = expf(a - mx);
    float ssum = w;
    #pragma unroll
    for (int off = 32; off > 0; off >>= 1) ssum += __shfl_xor(ssum, off, 64);
    float wn = w / (ssum + 1e-16f);
    float wsf = __shfl(wn, deg, 64);     // self-loop weight (deg wave-uniform, lane active)

    // phase B
    int g = lane >> 4;      // edge group 0..3
    int cl = lane & 15;     // col-block: cols [cl*8, cl*8+8)
    float ac0 = 0.f, ac1 = 0.f, ac2 = 0.f, ac3 = 0.f;
    float ac4 = 0.f, ac5 = 0.f, ac6 = 0.f, ac7 = 0.f;

    if (g == 0) {           // self row, counted once
        uint4 v = tab[(size_t)n * 16 + cl];
        ac0 += wsf * bf2f_lo(v.x); ac1 += wsf * bf2f_hi(v.x);
        ac2 += wsf * bf2f_lo(v.y); ac3 += wsf * bf2f_hi(v.y);
        ac4 += wsf * bf2f_lo(v.z); ac5 += wsf * bf2f_hi(v.z);
        ac6 += wsf * bf2f_lo(v.w); ac7 += wsf * bf2f_hi(v.w);
    }

    int niter = (deg + 3) >> 2;          // wave-uniform trip count
    for (int k = 0; k < niter; k++) {
        int i = g + 4 * k;
        bool valid = (i < deg);
        int idx = valid ? i : 0;         // clamp shfl source to an active lane
        float wi = __shfl(wn, idx, 64);
        int   si = __shfl(s, idx, 64);
        if (!valid) wi = 0.0f;           // masked tail contributes nothing
        uint4 v = tab[(size_t)si * 16 + cl];
        ac0 += wi * bf2f_lo(v.x); ac1 += wi * bf2f_hi(v.x);
        ac2 += wi * bf2f_lo(v.y); ac3 += wi * bf2f_hi(v.y);
        ac4 += wi * bf2f_lo(v.z); ac5 += wi * bf2f_hi(v.z);
        ac6 += wi * bf2f_lo(v.w); ac7 += wi * bf2f_hi(v.w);
    }

    // cross-group reduction (groups hold same cols at lane offsets 16/32/48)
    #pragma unroll
    for (int off = 16; off < 64; off <<= 1) {
        ac0 += __shfl_xor(ac0, off, 64); ac1 += __shfl_xor(ac1, off, 64);
        ac2 += __shfl_xor(ac2, off, 64); ac3 += __shfl_xor(ac3, off, 64);
        ac4 += __shfl_xor(ac4, off, 64); ac5 += __shfl_xor(ac5, off, 64);
        ac6 += __shfl_xor(ac6, off, 64); ac7 += __shfl_xor(ac7, off, 64);
    }
    if (g == 0) {
        float* op = out + (size_t)n * DIM + cl * 8;
        float4 o0; o0.x = ac0; o0.y = ac1; o0.z = ac2; o0.w = ac3;
        float4 o1; o1.x = ac4; o1.y = ac5; o1.z = ac6; o1.w = ac7;
        *(float4*)op = o0;
        *(float4*)(op + 4) = o1;
    }
}

extern "C" void kernel_launch(void* const* d_in, const int* in_sizes, int n_in,
                              void* d_out, int out_size, void* d_ws, size_t ws_size,
                              hipStream_t stream) {
    const float* x     = (const float*)d_in[0];
    const int*   ei    = (const int*)d_in[1];   // [2, E]
    const int*   label = (const int*)d_in[2];
    const float* W     = (const float*)d_in[3]; // [7, D, D]
    const float* att   = (const float*)d_in[4]; // [1, 1, 2D]
    float* out = (float*)d_out;

    const int* src = ei;
    const int* dst = ei + N_EDGES;

    // workspace (~27 MB). oxh doubles as xh (in-place tile overwrite, wave-local).
    char* w = (char*)d_ws;
    unsigned short* oxh    = (unsigned short*)w; w += sizeof(unsigned short) * (size_t)N_NODES * DIM;
    unsigned short* Wt     = (unsigned short*)w; w += sizeof(unsigned short) * 7 * DIM * DIM;
    unsigned short* bucket = (unsigned short*)w; w += sizeof(unsigned short) * (size_t)N_NODES * DEG_CAP;
    unsigned int*   binned = (unsigned int*)w;   w += sizeof(unsigned int) * (size_t)BINS * BIN_CAP;
    float* ai        = (float*)w;  w += sizeof(float) * N_NODES;
    float* aj        = (float*)w;  w += sizeof(float) * N_NODES;
    int*   cnt       = (int*)w;    w += sizeof(int) * N_NODES;
    int*   node_list = (int*)w;    w += sizeof(int) * (size_t)8 * N_NODES;
    // zero-region: lab_cnt(8) + bin_cur(BINS) contiguous, one memset
    int*   lab_cnt   = (int*)w;    w += sizeof(int) * 8;
    int*   bin_cur   = (int*)w;    w += sizeof(int) * BINS;

    hipMemsetAsync(lab_cnt, 0, sizeof(int) * (8 + BINS), stream);

    phase1_kernel<<<P1_GRID, 256, 0, stream>>>(x, src, dst, label, W,
                                               oxh, Wt, bin_cur, binned, lab_cnt, node_list);

    phase2_kernel<<<P2_GRID, 256, 0, stream>>>(x, att, lab_cnt, node_list, Wt,
                                               bin_cur, binned, oxh, ai, aj, cnt, bucket);

    gather6_kernel<<<(N_NODES + 3) / 4, 256, 0, stream>>>(cnt, bucket, ai, aj,
                                                          (const uint4*)oxh, out);
}